// Round 3
// baseline (180.416 us; speedup 1.0000x reference)
//
#include <hip/hip_runtime.h>
#include <math.h>

#define BATCH 65536
#define LHIST 128
#define HFUT  32
#define CH    16          // history chunk length (steps staged per DMA burst)

__device__ __forceinline__ float softplusf(float x) {
    // log(1+e^x), numerically stable; matches jax.nn.softplus (uniform, runs once)
    return fmaxf(x, 0.0f) + log1pf(expf(-fabsf(x)));
}

// Direct global->LDS DMA, 16B per lane. LDS dest is WAVE-UNIFORM base;
// HW deposits lane L's 16B at base + L*16. Global src is per-lane.
__device__ __forceinline__ void gload16(const float* g, float* l) {
    __builtin_amdgcn_global_load_lds(
        (const __attribute__((address_space(1))) void*)g,
        (__attribute__((address_space(3))) void*)l, 16, 0, 0);
}

// 65536 threads = 1024 waves on 1024 SIMDs -> structurally 1 wave/SIMD.
// All latency hiding must come from in-wave pipelining. Round-2 showed a
// REGISTER double-buffer can't hold the pipeline (spills at 128 VGPR, +5MB
// scratch, 2.3x slower). This version pipelines through LDS instead:
// per-wave private double buffer, global_load_lds DMA (zero VGPR for
// in-flight data), counted vmcnt waits (never 0 inside the loop) so the
// next chunk streams from HBM while the current chunk computes.
__global__ __launch_bounds__(256, 1) void kalman_fwd(
    const float* __restrict__ v_hist,
    const float* __restrict__ dt_hist,
    const float* __restrict__ x_obs,
    const float* __restrict__ v_fut,
    const float* __restrict__ dt_fut,
    const float* __restrict__ theta,
    float* __restrict__ out)
{
    const int b    = blockIdx.x * blockDim.x + threadIdx.x;
    const int lane = threadIdx.x & 63;
    const int wid  = threadIdx.x >> 6;

    // LDS: 4 waves x 2 buffers x 4096 floats (16KB).  Within a hist buffer:
    // array a (v,dt,y) at a*1024, group j (4 steps) at j*256, lane at lane*4.
    // Future staging reuses buf0: vf at j*256 (j=0..7), df at 2048 + j*256.
    __shared__ __align__(16) float lds[32768];    // 128 KiB (160 available, 1 block/CU)
    const int wbase = wid * 8192;

    // ---- uniform parameter transforms (once per thread, wave-uniform) ----
    const float alpha = 1.0f / (1.0f + expf(-theta[0]));
    const float c     = softplusf(theta[1]);
    const float kappa = softplusf(theta[2]);
    const float vc    = softplusf(theta[3]);       // VC_MIN = 0
    const float qx    = expf(theta[4]);
    const float qu    = expf(theta[5]);
    const float Rn    = expf(theta[6]);
    const float qs    = expf(theta[7]);
    const float p0xx  = expf(theta[8]);
    const float p0uu  = expf(theta[9]);
    const float a1    = softplusf(theta[10]);
    const float d1    = softplusf(theta[11]);
    const float d2    = softplusf(theta[12]);
    const float d3    = softplusf(theta[13]);
    const float b1    = theta[14];
    const float b2    = theta[15];
    const float beta  = theta[16];
    const float rho_m = tanhf(theta[17]);
    const float qm    = expf(theta[18]);
    const float p0mm  = expf(theta[19]);
    const float vc2   = vc * vc;
    const float qxs   = qs * qx;
    const float qus   = qs * qu;
    const float rm2   = rho_m * rho_m;
    const float nal2e = -alpha * 1.44269504088896340736f;  // exp(-a*dt)=exp2(nal2e*dt)

    // ---- per-thread state: s = (x,u,m); P symmetric 3x3 (6 uniques) ----
    float sx = 0.0f, su = 0.0f, sm = 0.0f;
    float p00 = p0xx, p01 = 0.0f, p02 = 0.0f, p11 = p0uu, p12 = 0.0f, p22 = p0mm;

    auto predict = [&](float v, float dv, float dt_raw) {
        float dt  = fmaxf(dt_raw, 1e-6f);
        float rho = __builtin_amdgcn_exp2f(nal2e * dt);
        float forcing = fmaxf(v * v - vc2, 0.0f);
        float cl = -a1 * su + b1 * v + b2 * dv
                 - d1 * su * su - d2 * su * fabsf(v) - d3 * su * fabsf(su);
        float kdt = kappa * dt;
        float x_p = sx + su * dt;
        float u_p = rho * su - kdt * sx + c * forcing * dt + cl * dt + beta * sm;
        float m_p = rho_m * sm;
        float f0 = p00 + dt * p01;
        float f1 = p01 + dt * p11;
        float f2 = p02 + dt * p12;
        float g0 = -kdt * p00 + rho * p01 + beta * p02;
        float g1 = -kdt * p01 + rho * p11 + beta * p12;
        float g2 = -kdt * p02 + rho * p12 + beta * p22;
        float n00 = f0 + dt * f1 + qxs * dt;
        float n01 = -kdt * f0 + rho * f1 + beta * f2;
        float n02 = rho_m * f2;
        float n11 = -kdt * g0 + rho * g1 + beta * g2 + qus * dt;
        float n12 = rho_m * g2;
        float n22 = rm2 * p22 + qm;
        sx = x_p; su = u_p; sm = m_p;
        p00 = n00; p01 = n01; p02 = n02; p11 = n11; p12 = n12; p22 = n22;
    };

    auto update = [&](float y) {
        float innov = y - sx;
        float S    = p00 + Rn;
        float Sinv = __builtin_amdgcn_rcpf(S);
        float K0 = p00 * Sinv, K1 = p01 * Sinv, K2 = p02 * Sinv;
        sx += K0 * innov; su += K1 * innov; sm += K2 * innov;
        float a = 1.0f - K0;
        float n00 = a * a * p00 + Rn * K0 * K0;
        float n01 = a * (p01 - K1 * p00) + Rn * K0 * K1;
        float n02 = a * (p02 - K2 * p00) + Rn * K0 * K2;
        float n11 = S * K1 * K1 - 2.0f * K1 * p01 + p11;
        float n12 = S * K1 * K2 - K2 * p01 - K1 * p02 + p12;
        float n22 = S * K2 * K2 - 2.0f * K2 * p02 + p22;
        p00 = n00; p01 = n01; p02 = n02; p11 = n11; p12 = n12; p22 = n22;
    };

    const float* vrow = v_hist  + (size_t)b * LHIST;
    const float* drow = dt_hist + (size_t)b * LHIST;
    const float* yrow = x_obs   + (size_t)b * LHIST;

    // stage history chunk k into buffer `buf` (12 DMA ops, 16B/lane each)
    auto stage_hist = [&](int k, int buf) {
        float* base = &lds[wbase + buf * 4096];
        #pragma unroll
        for (int j = 0; j < 4; ++j) {
            gload16(vrow + k * CH + 4 * j, base +        j * 256);
            gload16(drow + k * CH + 4 * j, base + 1024 + j * 256);
            gload16(yrow + k * CH + 4 * j, base + 2048 + j * 256);
        }
    };

    // pull a staged chunk from LDS into per-step locals (cheap ds_read_b128s;
    // compiler may sink these freely -- LDS latency is ~tens of cycles)
    float cv[CH], cd[CH], cy[CH];
    auto read_chunk = [&](int buf) {
        const float* base = &lds[wbase + buf * 4096 + lane * 4];
        #pragma unroll
        for (int j = 0; j < 4; ++j) {
            *(float4*)&cv[4 * j] = *(const float4*)(base +        j * 256);
            *(float4*)&cd[4 * j] = *(const float4*)(base + 1024 + j * 256);
            *(float4*)&cy[4 * j] = *(const float4*)(base + 2048 + j * 256);
        }
    };

    // drain any stray VMEM (theta loads etc.) so in-loop vmcnt counting is
    // exact: after this point the ONLY vmcnt ops are our DMA stages.
    asm volatile("s_waitcnt vmcnt(0)" ::: "memory");
    __builtin_amdgcn_sched_barrier(0);

    float v_bridge = 0.0f, dv_bridge = 0.0f;

    // ---- prologue: chunk 0 ----
    stage_hist(0, 0);
    stage_hist(1, 1);
    asm volatile("s_waitcnt vmcnt(12)" ::: "memory");   // chunk 0 landed; chunk 1 in flight
    __builtin_amdgcn_sched_barrier(0);
    read_chunk(0);
    sx = cy[0];                                    // s0.x = x_obs[b][0]
    predict(cv[0], 0.0f, cd[1]); update(cy[1]);    // t = 0
    #pragma unroll
    for (int i = 1; i < CH - 1; ++i) {             // t = 1..14
        predict(cv[i], cv[i] - cv[i - 1], cd[i + 1]); update(cy[i + 1]);
    }
    v_bridge  = cv[CH - 1];
    dv_bridge = cv[CH - 1] - cv[CH - 2];

    // ---- chunks 1..6: stage k+1 into the buffer compute(k) is NOT reading,
    // wait vmcnt(12) (= chunk k fully landed, chunk k+1 still streaming) ----
    #pragma unroll 1
    for (int k = 1; k < 7; ++k) {
        asm volatile("s_waitcnt lgkmcnt(0)" ::: "memory");  // no pending reads on buf being overwritten
        stage_hist(k + 1, (k + 1) & 1);
        asm volatile("s_waitcnt vmcnt(12)" ::: "memory");
        __builtin_amdgcn_sched_barrier(0);
        read_chunk(k & 1);
        predict(v_bridge, dv_bridge, cd[0]); update(cy[0]);               // t=16k-1
        predict(cv[0], cv[0] - v_bridge, cd[1]); update(cy[1]);           // t=16k
        #pragma unroll
        for (int i = 1; i < CH - 1; ++i) {                                // t=16k+i
            predict(cv[i], cv[i] - cv[i - 1], cd[i + 1]); update(cy[i + 1]);
        }
        v_bridge  = cv[CH - 1];
        dv_bridge = cv[CH - 1] - cv[CH - 2];
    }

    // ---- chunk 7 (in buf1): stage FUTURE inputs into buf0 under it ----
    {
        asm volatile("s_waitcnt lgkmcnt(0)" ::: "memory");
        const float* vfrow = v_fut  + (size_t)b * HFUT;
        const float* dfrow = dt_fut + (size_t)b * HFUT;
        float* base = &lds[wbase];                  // buf0: vf at 0, df at +2048
        #pragma unroll
        for (int j = 0; j < 8; ++j) gload16(vfrow + 4 * j, base +        j * 256);
        #pragma unroll
        for (int j = 0; j < 8; ++j) gload16(dfrow + 4 * j, base + 2048 + j * 256);
        asm volatile("s_waitcnt vmcnt(16)" ::: "memory");   // chunk 7 landed; fut in flight
        __builtin_amdgcn_sched_barrier(0);
        read_chunk(1);
        predict(v_bridge, dv_bridge, cd[0]); update(cy[0]);               // t=111
        predict(cv[0], cv[0] - v_bridge, cd[1]); update(cy[1]);           // t=112
        #pragma unroll
        for (int i = 1; i < CH - 1; ++i) {                                // t=112+i
            predict(cv[i], cv[i] - cv[i - 1], cd[i + 1]); update(cy[i + 1]);
        }
        v_bridge = cv[CH - 1];
    }
    // steps 0..126 done; v_bridge = v_hist[b][127]

    // ---- future rollout: inputs from LDS (already landed under chunk 7) ----
    asm volatile("s_waitcnt vmcnt(0)" ::: "memory");
    __builtin_amdgcn_sched_barrier(0);
    float vf[HFUT], df[HFUT];
    {
        const float* base = &lds[wbase + lane * 4];
        #pragma unroll
        for (int j = 0; j < 8; ++j) {
            *(float4*)&vf[4 * j] = *(const float4*)(base +        j * 256);
            *(float4*)&df[4 * j] = *(const float4*)(base + 2048 + j * 256);
        }
    }

    float oxp[HFUT], oxv[HFUT], oue[HFUT];
    float vp = v_bridge;
    #pragma unroll
    for (int j = 0; j < HFUT; ++j) {
        predict(vf[j], vf[j] - vp, df[j]);
        vp = vf[j];
        oxp[j] = sx; oxv[j] = p00; oue[j] = su;
    }

    // ---- back-to-back full-line burst stores (measured-ideal WRITE_SIZE) ----
    float4* xp = (float4*)(out + (size_t)b * HFUT);
    float4* xv = (float4*)(out + (size_t)BATCH * HFUT + (size_t)b * HFUT);
    float4* ue = (float4*)(out + 2 * (size_t)BATCH * HFUT + (size_t)b * HFUT);
    float4* OXP = (float4*)oxp; float4* OXV = (float4*)oxv; float4* OUE = (float4*)oue;
    #pragma unroll
    for (int i = 0; i < HFUT / 4; ++i) {
        xp[i] = OXP[i]; xv[i] = OXV[i]; ue[i] = OUE[i];
    }
}

extern "C" void kernel_launch(void* const* d_in, const int* in_sizes, int n_in,
                              void* d_out, int out_size, void* d_ws, size_t ws_size,
                              hipStream_t stream) {
    const float* v_hist  = (const float*)d_in[0];
    const float* dt_hist = (const float*)d_in[1];
    const float* x_obs   = (const float*)d_in[2];
    const float* v_fut   = (const float*)d_in[3];
    const float* dt_fut  = (const float*)d_in[4];
    const float* theta   = (const float*)d_in[5];
    float* out = (float*)d_out;

    dim3 grid(BATCH / 256), block(256);
    hipLaunchKernelGGL(kalman_fwd, grid, block, 0, stream,
                       v_hist, dt_hist, x_obs, v_fut, dt_fut, theta, out);
}